// Round 3
// baseline (341.469 us; speedup 1.0000x reference)
//
#include <hip/hip_runtime.h>
#include <stdint.h>

// QuickDistogram: N=32768, K=64, C=256, PAIR=32, HID=64, BINS=16, CLIP=32.
// Outputs: log_p [N*K*16] then dmap [N*K] (fp32).
#define N_RES 32768
#define KNEI  64
#define CFEAT 256
#define PAIRD 32
#define HIDD  64
#define NBINS 16
#define CLIPV 32
#define NGROUPS (N_RES * KNEI / 16)   // 131072 groups of 16 pairs

typedef __attribute__((ext_vector_type(8))) short  short8;   // 8 bf16 = MFMA A/B frag
typedef __attribute__((ext_vector_type(4))) float  float4_t; // MFMA C/D frag

union U8 { uint32_t u[4]; short8 s8; };

// pack two fp32 -> bf16x2, round-half-up.  low16 = a, high16 = b.
__device__ __forceinline__ uint32_t pkbf(float a, float b) {
    uint32_t ua = __float_as_uint(a) + 0x8000u;
    uint32_t ub = __float_as_uint(b) + 0x8000u;
    uint32_t d;
    const uint32_t sel = 0x07060302u;  // D = {ub.b3,ub.b2, ua.b3,ua.b2}
    asm("v_perm_b32 %0, %1, %2, %3" : "=v"(d) : "v"(ub), "v"(ua), "s"(sel));
    return d;
}
__device__ __forceinline__ float bflo(uint32_t w) { return __uint_as_float(w << 16); }
__device__ __forceinline__ float bfhi(uint32_t w) { return __uint_as_float(w & 0xFFFF0000u); }

__device__ __forceinline__ float fastrcp(float x) { return __builtin_amdgcn_rcpf(x); }
__device__ __forceinline__ float fexp2(float x)   { return __builtin_amdgcn_exp2f(x); }
__device__ __forceinline__ float flog2(float x)   { return __builtin_amdgcn_logf(x); }

// tanh-form GELU, exp2-folded (matches jax.nn.gelu approximate=True)
__device__ __forceinline__ float gelu_tanh(float x) {
    const float k1 = 2.3022082f;   // 2*0.7978845608*log2(e)
    const float k2 = 0.1029432f;   // k1*0.044715
    float x2 = x * x;
    float t  = __builtin_fmaf(k2, x2, k1);
    float e  = fexp2(x * t);
    float th = __builtin_fmaf(-2.0f, fastrcp(e + 1.0f), 1.0f);
    float hx = 0.5f * x;
    return __builtin_fmaf(hx, th, hx);
}

// ---------------------------------------------------------------------------
// Kernel 1: left/right = feat @ W_{l,r} (fp32 VALU, bf16 output tables) +
// packed meta dword + bf16 wpos table.  grid=512, block=256, 64 rows/block.
// ---------------------------------------------------------------------------
__global__ __launch_bounds__(256) void proj_kernel(
    const float* __restrict__ feat, const float* __restrict__ Wl,
    const float* __restrict__ Wr, const int* __restrict__ resi,
    const int* __restrict__ chain, const int* __restrict__ batch,
    const float* __restrict__ wpos,
    uint4* __restrict__ leftbf, uint4* __restrict__ rightbf,
    uint32_t* __restrict__ meta, uint32_t* __restrict__ wposbf)
{
    __shared__ __align__(16) float Wc[CFEAT * 64];
    const int tid = threadIdx.x;
    for (int idx = tid; idx < CFEAT * 32; idx += 256) {
        int k = idx >> 5, o = idx & 31;
        Wc[k * 64 + o]      = Wl[idx];
        Wc[k * 64 + 32 + o] = Wr[idx];
    }
    const int row_base = blockIdx.x * 64;
    if (tid < 64) {
        int r = row_base + tid;
        meta[r] = (uint32_t)resi[r] | ((uint32_t)chain[r] << 16)
                | ((uint32_t)batch[r] << 19);
    }
    if (blockIdx.x == 0) {
        for (int i = tid; i < (2 * CLIPV + 1) * PAIRD / 2; i += 256)
            wposbf[i] = pkbf(wpos[2 * i], wpos[2 * i + 1]);
    }
    __syncthreads();

    const int cb = (tid & 7) * 8;                    // 8 output cols
    const int r0 = row_base + (tid >> 3) * 2;        // 2 rows

    float acc[2][8];
#pragma unroll
    for (int r = 0; r < 2; ++r)
#pragma unroll
        for (int j = 0; j < 8; ++j) acc[r][j] = 0.f;

    for (int i = 0; i < CFEAT; i += 4) {
        float4_t f0 = *(const float4_t*)(feat + (size_t)r0 * CFEAT + i);
        float4_t f1 = *(const float4_t*)(feat + (size_t)(r0 + 1) * CFEAT + i);
#pragma unroll
        for (int s = 0; s < 4; ++s) {
            float4_t wa = *(const float4_t*)(Wc + (i + s) * 64 + cb);
            float4_t wb = *(const float4_t*)(Wc + (i + s) * 64 + cb + 4);
#pragma unroll
            for (int j = 0; j < 4; ++j) {
                acc[0][j]     += f0[s] * wa[j];
                acc[0][4 + j] += f0[s] * wb[j];
                acc[1][j]     += f1[s] * wa[j];
                acc[1][4 + j] += f1[s] * wb[j];
            }
        }
    }
#pragma unroll
    for (int r = 0; r < 2; ++r) {
        uint4 o;
        o.x = pkbf(acc[r][0], acc[r][1]);
        o.y = pkbf(acc[r][2], acc[r][3]);
        o.z = pkbf(acc[r][4], acc[r][5]);
        o.w = pkbf(acc[r][6], acc[r][7]);
        if (cb < 32) leftbf [(size_t)(r0 + r) * 4 + (cb >> 3)]        = o;
        else         rightbf[(size_t)(r0 + r) * 4 + ((cb - 32) >> 3)] = o;
    }
}

// ---------------------------------------------------------------------------
// Kernel 2: per-pair dcode -> LN -> MLP(MFMA bf16) -> log_softmax -> outputs.
// One wave = 16 pairs; lane (q=lane>>4, c=lane&15) holds dims 8q..8q+7 of
// pair c (MFMA B-frag).  bf16 gather tables (64B = 1 line/pair), 1-dword
// meta, and a depth-2 software pipeline hide gather latency.
// ---------------------------------------------------------------------------
__global__ __launch_bounds__(256, 8) void pair_kernel(
    const uint4* __restrict__ leftbf, const uint4* __restrict__ rightbf,
    const uint32_t* __restrict__ meta, const int* __restrict__ nbr,
    const uint32_t* __restrict__ wposbf,
    const float* __restrict__ lnS, const float* __restrict__ lnB,
    const float* __restrict__ W1, const float* __restrict__ b1,
    const float* __restrict__ W2, const float* __restrict__ b2,
    float* __restrict__ out_logp, float* __restrict__ out_dmap)
{
    __shared__ __align__(16) unsigned char Hbuf[4][16 * 144]; // wave-private H transpose
    __shared__ __align__(16) float b1p[HIDD];                 // b1 + lnB @ W1 (fp32)

    const int tid    = threadIdx.x;
    const int lane   = tid & 63;
    const int wlocal = tid >> 6;
    const int q      = lane >> 4;
    const int c      = lane & 15;

    // ---- preamble: fold ln_bias through W1 into b1' ----
    if (tid < HIDD) {
        float s = b1[tid];
        for (int k = 0; k < PAIRD; ++k)
            s = __builtin_fmaf(lnB[k], W1[k * HIDD + tid], s);
        b1p[tid] = s;
    }

    // ---- weight fragments: W1' = diag(ln_scale) @ W1, A-frag of W1'^T ----
    short8 w1a[4];
#pragma unroll
    for (int t = 0; t < 4; ++t) {
        U8 tmp;
#pragma unroll
        for (int v = 0; v < 4; ++v) {
            int k0 = q * 8 + 2 * v, k1 = k0 + 1;
            float a0 = lnS[k0] * W1[k0 * HIDD + 16 * t + c];
            float a1 = lnS[k1] * W1[k1 * HIDD + 16 * t + c];
            tmp.u[v] = pkbf(a0, a1);
        }
        w1a[t] = tmp.s8;
    }
    short8 w2a[2];                         // A-frag of W2^T, K-tile kt
#pragma unroll
    for (int kt = 0; kt < 2; ++kt) {
        U8 tmp;
#pragma unroll
        for (int v = 0; v < 4; ++v) {
            int k0 = kt * 32 + q * 8 + 2 * v;
            tmp.u[v] = pkbf(W2[k0 * NBINS + c], W2[(k0 + 1) * NBINS + c]);
        }
        w2a[kt] = tmp.s8;
    }
    const float4_t b2f = *(const float4_t*)(b2 + 4 * q);   // C-init for layer 2

    __syncthreads();   // b1p ready

    const int wglobal = (blockIdx.x * 256 + tid) >> 6;  // 0..8191
    const int stride  = 8192;                            // waves in grid
    // NGROUPS / stride == 16 iterations exactly.

    // ---- pipeline prologue: stage group it=0 ----
    uint4 lfS, rfS, pwS; float mskS;
    {
        const int pbase = wglobal * 16;
        const int n = pbase >> 6, p = pbase + c;
        const int nb = nbr[p];
        const uint32_t mn = meta[n];
        const uint32_t mb = meta[nb];
        lfS = leftbf [(size_t)n  * 4 + q];
        rfS = rightbf[(size_t)nb * 4 + q];
        int rel = min(max((int)(mb & 0xFFFFu) - (int)(mn & 0xFFFFu), -CLIPV), CLIPV) + CLIPV;
        mskS = (((mb ^ mn) & 0xFFFF0000u) == 0u) ? 1.0f : 0.0f;
        pwS = *(const uint4*)(wposbf + rel * 16 + q * 4);
    }

    for (int it = 0; it < 16; ++it) {
        const int gc = wglobal + it * stride;
        const int p  = gc * 16 + c;

        // ---- issue next group's independent loads (wraps on last iter) ----
        const int gn = wglobal + ((it + 1) & 15) * stride;
        const int nn = (gn * 16) >> 6, pn = gn * 16 + c;
        const int nbN = nbr[pn];
        const uint32_t mnN = meta[nn];
        const uint4 lfN = leftbf[(size_t)nn * 4 + q];

        // current stage -> locals
        const uint4 lf = lfS, rf = rfS, pw = pwS;
        const float msk = mskS;

        // ---- dependent next loads (nbN issued above) ----
        const uint32_t mbN = meta[nbN];
        const uint4 rfN = rightbf[(size_t)nbN * 4 + q];

        // ---- unpack bf16 + build dcode dims 8q..8q+7 of pair c ----
        const uint32_t la[4] = {lf.x, lf.y, lf.z, lf.w};
        const uint32_t ra[4] = {rf.x, rf.y, rf.z, rf.w};
        const uint32_t pa[4] = {pw.x, pw.y, pw.z, pw.w};
        float d[8];
#pragma unroll
        for (int v = 0; v < 4; ++v) {
            d[2 * v]     = __builtin_fmaf(msk, bflo(pa[v]), bflo(la[v]) + bflo(ra[v]));
            d[2 * v + 1] = __builtin_fmaf(msk, bfhi(pa[v]), bfhi(la[v]) + bfhi(ra[v]));
        }

        // ---- LayerNorm stats over 32 dims (4 quads of pair c) ----
        float s1 = 0.f, s2 = 0.f;
#pragma unroll
        for (int j = 0; j < 8; ++j) { s1 += d[j]; s2 = __builtin_fmaf(d[j], d[j], s2); }
        s1 += __shfl_xor(s1, 16, 64);  s1 += __shfl_xor(s1, 32, 64);
        s2 += __shfl_xor(s2, 16, 64);  s2 += __shfl_xor(s2, 32, 64);
        const float mu   = s1 * (1.0f / 32.0f);
        const float var  = __builtin_fmaf(-mu, mu, s2 * (1.0f / 32.0f));
        const float rstd = __builtin_amdgcn_rsqf(var + 1e-5f);
        const float sh   = -mu * rstd;

        U8 dpack;
#pragma unroll
        for (int v = 0; v < 4; ++v) {
            float nA = __builtin_fmaf(d[2 * v],     rstd, sh);
            float nB = __builtin_fmaf(d[2 * v + 1], rstd, sh);
            dpack.u[v] = pkbf(nA, nB);
        }
        const short8 dfrag = dpack.s8;   // B-frag: B[k=q*8+j][n=c]

        // ---- layer 1 (bias b1' as MFMA C operand, broadcast LDS read) ----
        float4_t hacc[4];
#pragma unroll
        for (int t = 0; t < 4; ++t) {
            float4_t c1 = *(const float4_t*)(b1p + 16 * t + 4 * q);
            hacc[t] = __builtin_amdgcn_mfma_f32_16x16x32_bf16(w1a[t], dfrag, c1, 0, 0, 0);
        }

        // ---- next group's wpos gather (mbN has had MFMA time to land) ----
        const int relN = min(max((int)(mbN & 0xFFFFu) - (int)(mnN & 0xFFFFu),
                                 -CLIPV), CLIPV) + CLIPV;
        const float mskN = (((mbN ^ mnN) & 0xFFFF0000u) == 0u) ? 1.0f : 0.0f;
        const uint4 pwN = *(const uint4*)(wposbf + relN * 16 + q * 4);

        // ---- GELU + pack to LDS (transpose to layer-2 B-frag layout) ----
        unsigned char* hb = &Hbuf[wlocal][0] + c * 144;
#pragma unroll
        for (int t = 0; t < 4; ++t) {
            float g0 = gelu_tanh(hacc[t][0]);
            float g1 = gelu_tanh(hacc[t][1]);
            float g2 = gelu_tanh(hacc[t][2]);
            float g3 = gelu_tanh(hacc[t][3]);
            uint2 w; w.x = pkbf(g0, g1); w.y = pkbf(g2, g3);
            *(uint2*)(hb + 32 * t + 8 * q) = w;   // hid 16t+4q+0..3 of pair c
        }
        const short8 hf0 = *(const short8*)(hb + 16 * q);        // hid 8q..8q+7
        const short8 hf1 = *(const short8*)(hb + 64 + 16 * q);   // hid 32+8q..

        // ---- layer 2 (b2 as C operand): lane holds bins 4q..4q+3 of pair c ----
        float4_t lacc;
        lacc = __builtin_amdgcn_mfma_f32_16x16x32_bf16(w2a[0], hf0, b2f,  0, 0, 0);
        lacc = __builtin_amdgcn_mfma_f32_16x16x32_bf16(w2a[1], hf1, lacc, 0, 0, 0);

        // ---- log-softmax without max-subtraction (logits are O(+-10)) ----
        const float LOG2E = 1.4426950408889634f, LN2 = 0.6931471805599453f;
        float e[4];
#pragma unroll
        for (int r = 0; r < 4; ++r) e[r] = fexp2(lacc[r] * LOG2E);
        float ssum = (e[0] + e[1]) + (e[2] + e[3]);
        ssum += __shfl_xor(ssum, 16, 64);
        ssum += __shfl_xor(ssum, 32, 64);
        const float lse = flog2(ssum) * LN2;

        float4_t lp = {lacc[0] - lse, lacc[1] - lse, lacc[2] - lse, lacc[3] - lse};
        *(float4_t*)(out_logp + (size_t)p * NBINS + 4 * q) = lp;  // coalesced 1KB/wave

        const float step  = 22.0f / NBINS;
        const float cbase = (4 * q + 0.5f) * step;
        float dpart = e[0] * cbase + e[1] * (cbase + step)
                    + e[2] * (cbase + 2 * step) + e[3] * (cbase + 3 * step);
        dpart += __shfl_xor(dpart, 16, 64);
        dpart += __shfl_xor(dpart, 32, 64);
        if (q == 0) out_dmap[p] = dpart * fastrcp(ssum);

        // ---- rotate pipeline ----
        lfS = lfN; rfS = rfN; pwS = pwN; mskS = mskN;
    }
}

// ---------------------------------------------------------------------------
extern "C" void kernel_launch(void* const* d_in, const int* in_sizes, int n_in,
                              void* d_out, int out_size, void* d_ws, size_t ws_size,
                              hipStream_t stream) {
    const float* features = (const float*)d_in[0];
    const int*   resi     = (const int*)d_in[1];
    const int*   chain    = (const int*)d_in[2];
    const int*   batch    = (const int*)d_in[3];
    const int*   nbr      = (const int*)d_in[4];
    const float* W_left   = (const float*)d_in[5];
    const float* W_right  = (const float*)d_in[6];
    const float* W_pos    = (const float*)d_in[7];
    const float* ln_scale = (const float*)d_in[8];
    const float* ln_bias  = (const float*)d_in[9];
    const float* W1       = (const float*)d_in[10];
    const float* b1       = (const float*)d_in[11];
    const float* W2       = (const float*)d_in[12];
    const float* b2       = (const float*)d_in[13];

    // workspace layout (all 16B-aligned):
    char* ws = (char*)d_ws;
    uint4*    leftbf  = (uint4*)ws;                                   // 2 MB
    uint4*    rightbf = (uint4*)(ws + (size_t)N_RES * 64);            // 2 MB
    uint32_t* meta    = (uint32_t*)(ws + (size_t)2 * N_RES * 64);     // 128 KB
    uint32_t* wposbf  = (uint32_t*)(ws + (size_t)2 * N_RES * 64 + N_RES * 4); // 4.2 KB

    float* out_logp = (float*)d_out;
    float* out_dmap = out_logp + (size_t)N_RES * KNEI * NBINS;

    proj_kernel<<<N_RES / 64, 256, 0, stream>>>(features, W_left, W_right,
                                                resi, chain, batch, W_pos,
                                                leftbf, rightbf, meta, wposbf);
    pair_kernel<<<2048, 256, 0, stream>>>(leftbf, rightbf, meta, nbr, wposbf,
                                          ln_scale, ln_bias, W1, b1, W2, b2,
                                          out_logp, out_dmap);
}

// Round 4
// 290.163 us; speedup vs baseline: 1.1768x; 1.1768x over previous
//
#include <hip/hip_runtime.h>
#include <stdint.h>

// QuickDistogram: N=32768, K=64, C=256, PAIR=32, HID=64, BINS=16, CLIP=32.
// Outputs: log_p [N*K*16] then dmap [N*K] (fp32).
#define N_RES 32768
#define KNEI  64
#define CFEAT 256
#define PAIRD 32
#define HIDD  64
#define NBINS 16
#define CLIPV 32
#define NGROUPS (N_RES * KNEI / 16)   // 131072 groups of 16 pairs

typedef __attribute__((ext_vector_type(8))) short  short8;   // 8 bf16 = MFMA A/B frag
typedef __attribute__((ext_vector_type(4))) float  float4_t; // MFMA C/D frag

union U8 { uint32_t u[4]; short8 s8; };

// pack two fp32 -> bf16x2, round-half-up.  low16 = a, high16 = b.
__device__ __forceinline__ uint32_t pkbf(float a, float b) {
    uint32_t ua = __float_as_uint(a) + 0x8000u;
    uint32_t ub = __float_as_uint(b) + 0x8000u;
    uint32_t d;
    const uint32_t sel = 0x07060302u;  // D = {ub.b3,ub.b2, ua.b3,ua.b2}
    asm("v_perm_b32 %0, %1, %2, %3" : "=v"(d) : "v"(ub), "v"(ua), "s"(sel));
    return d;
}
__device__ __forceinline__ float bflo(uint32_t w) { return __uint_as_float(w << 16); }
__device__ __forceinline__ float bfhi(uint32_t w) { return __uint_as_float(w & 0xFFFF0000u); }

__device__ __forceinline__ float fastrcp(float x) { return __builtin_amdgcn_rcpf(x); }
__device__ __forceinline__ float fexp2(float x)   { return __builtin_amdgcn_exp2f(x); }
__device__ __forceinline__ float flog2(float x)   { return __builtin_amdgcn_logf(x); }

// tanh-form GELU, exp2-folded (matches jax.nn.gelu approximate=True)
__device__ __forceinline__ float gelu_tanh(float x) {
    const float k1 = 2.3022082f;   // 2*0.7978845608*log2(e)
    const float k2 = 0.1029432f;   // k1*0.044715
    float x2 = x * x;
    float t  = __builtin_fmaf(k2, x2, k1);
    float e  = fexp2(x * t);
    float th = __builtin_fmaf(-2.0f, fastrcp(e + 1.0f), 1.0f);
    float hx = 0.5f * x;
    return __builtin_fmaf(hx, th, hx);
}

// ---------------------------------------------------------------------------
// Kernel 1: left/right = feat @ W_{l,r} (fp32 VALU) -> bf16 tables, packed
// meta dword, bf16 wpos table.  grid=1024: blocks 0..511 do LEFT (and meta),
// 512..1023 do RIGHT.  32KB LDS/block -> 4 blocks/CU -> 4 waves/SIMD.
// Each thread: 1 row x 8 cols.
// ---------------------------------------------------------------------------
__global__ __launch_bounds__(256) void proj_kernel(
    const float* __restrict__ feat, const float* __restrict__ Wl,
    const float* __restrict__ Wr, const int* __restrict__ resi,
    const int* __restrict__ chain, const int* __restrict__ batch,
    const float* __restrict__ wpos,
    uint4* __restrict__ leftbf, uint4* __restrict__ rightbf,
    uint32_t* __restrict__ meta, uint32_t* __restrict__ wposbf)
{
    __shared__ __align__(16) float Wc[CFEAT * 32];   // 32 KB
    const int tid   = threadIdx.x;
    const int half  = blockIdx.x >> 9;               // 0 = left, 1 = right
    const int rb    = (blockIdx.x & 511) * 64;
    const float* W  = half ? Wr : Wl;
    uint4* outtb    = half ? rightbf : leftbf;

    for (int idx = tid; idx < CFEAT * 32; idx += 256)
        Wc[idx] = W[idx];
    if (half == 0 && tid < 64) {
        int r = rb + tid;
        meta[r] = (uint32_t)resi[r] | ((uint32_t)chain[r] << 16)
                | ((uint32_t)batch[r] << 19);
    }
    if (blockIdx.x == 0) {
        for (int i = tid; i < (2 * CLIPV + 1) * PAIRD / 2; i += 256)
            wposbf[i] = pkbf(wpos[2 * i], wpos[2 * i + 1]);
    }
    __syncthreads();

    const int cb  = (tid & 3) * 8;        // 8 of 32 output cols
    const int row = rb + (tid >> 2);      // 1 row

    float acc[8];
#pragma unroll
    for (int j = 0; j < 8; ++j) acc[j] = 0.f;

    for (int i = 0; i < CFEAT; i += 4) {
        float4_t f = *(const float4_t*)(feat + (size_t)row * CFEAT + i);
#pragma unroll
        for (int s = 0; s < 4; ++s) {
            float4_t wa = *(const float4_t*)(Wc + (i + s) * 32 + cb);
            float4_t wb = *(const float4_t*)(Wc + (i + s) * 32 + cb + 4);
#pragma unroll
            for (int j = 0; j < 4; ++j) {
                acc[j]     = __builtin_fmaf(f[s], wa[j], acc[j]);
                acc[4 + j] = __builtin_fmaf(f[s], wb[j], acc[4 + j]);
            }
        }
    }
    uint2 o;
    o.x = pkbf(acc[0], acc[1]);
    o.y = pkbf(acc[2], acc[3]);
    uint2 o2;
    o2.x = pkbf(acc[4], acc[5]);
    o2.y = pkbf(acc[6], acc[7]);
    uint2* dst = (uint2*)outtb + (size_t)row * 8 + (cb >> 2);
    dst[0] = o;
    dst[1] = o2;
}

// ---------------------------------------------------------------------------
// Kernel 2: per-pair dcode -> LN -> MLP(MFMA bf16) -> log_softmax -> outputs.
// One wave = 16 pairs; lane (q=lane>>4, c=lane&15) holds dims 8q..8q+7 of
// pair c (MFMA B-frag).  bf16 gather tables (64B = 1 line/pair), 1-dword
// meta.  NT stores for outputs + NT load for nbr keep L2 for the gather
// tables (no write-allocate RFO, no streaming eviction).
// ---------------------------------------------------------------------------
__global__ __launch_bounds__(256, 8) void pair_kernel(
    const uint4* __restrict__ leftbf, const uint4* __restrict__ rightbf,
    const uint32_t* __restrict__ meta, const int* __restrict__ nbr,
    const uint32_t* __restrict__ wposbf,
    const float* __restrict__ lnS, const float* __restrict__ lnB,
    const float* __restrict__ W1, const float* __restrict__ b1,
    const float* __restrict__ W2, const float* __restrict__ b2,
    float* __restrict__ out_logp, float* __restrict__ out_dmap)
{
    __shared__ __align__(16) unsigned char Hbuf[4][16 * 144]; // wave-private H transpose
    __shared__ __align__(16) float b1p[HIDD];                 // b1 + lnB @ W1 (fp32)

    const int tid    = threadIdx.x;
    const int lane   = tid & 63;
    const int wlocal = tid >> 6;
    const int q      = lane >> 4;
    const int c      = lane & 15;

    // ---- preamble: fold ln_bias through W1 into b1' ----
    if (tid < HIDD) {
        float s = b1[tid];
        for (int k = 0; k < PAIRD; ++k)
            s = __builtin_fmaf(lnB[k], W1[k * HIDD + tid], s);
        b1p[tid] = s;
    }

    // ---- weight fragments: W1' = diag(ln_scale) @ W1, A-frag of W1'^T ----
    short8 w1a[4];
#pragma unroll
    for (int t = 0; t < 4; ++t) {
        U8 tmp;
#pragma unroll
        for (int v = 0; v < 4; ++v) {
            int k0 = q * 8 + 2 * v, k1 = k0 + 1;
            float a0 = lnS[k0] * W1[k0 * HIDD + 16 * t + c];
            float a1 = lnS[k1] * W1[k1 * HIDD + 16 * t + c];
            tmp.u[v] = pkbf(a0, a1);
        }
        w1a[t] = tmp.s8;
    }
    short8 w2a[2];                         // A-frag of W2^T, K-tile kt
#pragma unroll
    for (int kt = 0; kt < 2; ++kt) {
        U8 tmp;
#pragma unroll
        for (int v = 0; v < 4; ++v) {
            int k0 = kt * 32 + q * 8 + 2 * v;
            tmp.u[v] = pkbf(W2[k0 * NBINS + c], W2[(k0 + 1) * NBINS + c]);
        }
        w2a[kt] = tmp.s8;
    }
    const float4_t b2f = *(const float4_t*)(b2 + 4 * q);   // C-init for layer 2

    __syncthreads();   // b1p ready

    const int wglobal = (blockIdx.x * 256 + tid) >> 6;
    const int nwaves  = (gridDim.x * 256) >> 6;

    for (int g = wglobal; g < NGROUPS; g += nwaves) {
        const int pbase = g * 16;
        const int n = pbase >> 6;             // 4 groups per residue n
        const int p = pbase + c;
        const int nb = __builtin_nontemporal_load(nbr + p);

        const uint32_t mn = meta[n];          // wave-uniform (L1 hit)
        const uint32_t mb = meta[nb];
        const uint4 lf = leftbf [(size_t)n  * 4 + q];   // broadcast 64B/wave
        const uint4 rf = rightbf[(size_t)nb * 4 + q];   // 1 line per pair

        const int rel = min(max((int)(mb & 0xFFFFu) - (int)(mn & 0xFFFFu),
                                -CLIPV), CLIPV) + CLIPV;
        const float msk = (((mb ^ mn) & 0xFFFF0000u) == 0u) ? 1.0f : 0.0f;
        const uint4 pw = *(const uint4*)(wposbf + rel * 16 + q * 4);  // 4KB L1-res

        // ---- unpack bf16 + build dcode dims 8q..8q+7 of pair c ----
        const uint32_t la[4] = {lf.x, lf.y, lf.z, lf.w};
        const uint32_t ra[4] = {rf.x, rf.y, rf.z, rf.w};
        const uint32_t pa[4] = {pw.x, pw.y, pw.z, pw.w};
        float d[8];
#pragma unroll
        for (int v = 0; v < 4; ++v) {
            d[2 * v]     = __builtin_fmaf(msk, bflo(pa[v]), bflo(la[v]) + bflo(ra[v]));
            d[2 * v + 1] = __builtin_fmaf(msk, bfhi(pa[v]), bfhi(la[v]) + bfhi(ra[v]));
        }

        // ---- LayerNorm stats over 32 dims (4 quads of pair c) ----
        float s1 = 0.f, s2 = 0.f;
#pragma unroll
        for (int j = 0; j < 8; ++j) { s1 += d[j]; s2 = __builtin_fmaf(d[j], d[j], s2); }
        s1 += __shfl_xor(s1, 16, 64);  s1 += __shfl_xor(s1, 32, 64);
        s2 += __shfl_xor(s2, 16, 64);  s2 += __shfl_xor(s2, 32, 64);
        const float mu   = s1 * (1.0f / 32.0f);
        const float var  = __builtin_fmaf(-mu, mu, s2 * (1.0f / 32.0f));
        const float rstd = __builtin_amdgcn_rsqf(var + 1e-5f);
        const float sh   = -mu * rstd;

        U8 dpack;
#pragma unroll
        for (int v = 0; v < 4; ++v) {
            float nA = __builtin_fmaf(d[2 * v],     rstd, sh);
            float nB = __builtin_fmaf(d[2 * v + 1], rstd, sh);
            dpack.u[v] = pkbf(nA, nB);
        }
        const short8 dfrag = dpack.s8;   // B-frag: B[k=q*8+j][n=c]

        // ---- layer 1 (bias b1' as MFMA C operand, broadcast LDS read) ----
        float4_t hacc[4];
#pragma unroll
        for (int t = 0; t < 4; ++t) {
            float4_t c1 = *(const float4_t*)(b1p + 16 * t + 4 * q);
            hacc[t] = __builtin_amdgcn_mfma_f32_16x16x32_bf16(w1a[t], dfrag, c1, 0, 0, 0);
        }

        // ---- GELU + pack to LDS (transpose to layer-2 B-frag layout) ----
        unsigned char* hb = &Hbuf[wlocal][0] + c * 144;
#pragma unroll
        for (int t = 0; t < 4; ++t) {
            float g0 = gelu_tanh(hacc[t][0]);
            float g1 = gelu_tanh(hacc[t][1]);
            float g2 = gelu_tanh(hacc[t][2]);
            float g3 = gelu_tanh(hacc[t][3]);
            uint2 w; w.x = pkbf(g0, g1); w.y = pkbf(g2, g3);
            *(uint2*)(hb + 32 * t + 8 * q) = w;   // hid 16t+4q+0..3 of pair c
        }
        const short8 hf0 = *(const short8*)(hb + 16 * q);        // hid 8q..8q+7
        const short8 hf1 = *(const short8*)(hb + 64 + 16 * q);   // hid 32+8q..

        // ---- layer 2 (b2 as C operand): lane holds bins 4q..4q+3 of pair c ----
        float4_t lacc;
        lacc = __builtin_amdgcn_mfma_f32_16x16x32_bf16(w2a[0], hf0, b2f,  0, 0, 0);
        lacc = __builtin_amdgcn_mfma_f32_16x16x32_bf16(w2a[1], hf1, lacc, 0, 0, 0);

        // ---- log-softmax without max-subtraction (logits are O(+-10)) ----
        const float LOG2E = 1.4426950408889634f, LN2 = 0.6931471805599453f;
        float e[4];
#pragma unroll
        for (int r = 0; r < 4; ++r) e[r] = fexp2(lacc[r] * LOG2E);
        float ssum = (e[0] + e[1]) + (e[2] + e[3]);
        ssum += __shfl_xor(ssum, 16, 64);
        ssum += __shfl_xor(ssum, 32, 64);
        const float lse = flog2(ssum) * LN2;

        // ---- NT stores: bypass/no-allocate L2, keep it for the gathers ----
        float4_t lp = {lacc[0] - lse, lacc[1] - lse, lacc[2] - lse, lacc[3] - lse};
        __builtin_nontemporal_store(lp, (float4_t*)(out_logp + (size_t)p * NBINS + 4 * q));

        const float step  = 22.0f / NBINS;
        const float cbase = (4 * q + 0.5f) * step;
        float dpart = e[0] * cbase + e[1] * (cbase + step)
                    + e[2] * (cbase + 2 * step) + e[3] * (cbase + 3 * step);
        dpart += __shfl_xor(dpart, 16, 64);
        dpart += __shfl_xor(dpart, 32, 64);
        if (q == 0)
            __builtin_nontemporal_store(dpart * fastrcp(ssum), out_dmap + p);
    }
}

// ---------------------------------------------------------------------------
extern "C" void kernel_launch(void* const* d_in, const int* in_sizes, int n_in,
                              void* d_out, int out_size, void* d_ws, size_t ws_size,
                              hipStream_t stream) {
    const float* features = (const float*)d_in[0];
    const int*   resi     = (const int*)d_in[1];
    const int*   chain    = (const int*)d_in[2];
    const int*   batch    = (const int*)d_in[3];
    const int*   nbr      = (const int*)d_in[4];
    const float* W_left   = (const float*)d_in[5];
    const float* W_right  = (const float*)d_in[6];
    const float* W_pos    = (const float*)d_in[7];
    const float* ln_scale = (const float*)d_in[8];
    const float* ln_bias  = (const float*)d_in[9];
    const float* W1       = (const float*)d_in[10];
    const float* b1       = (const float*)d_in[11];
    const float* W2       = (const float*)d_in[12];
    const float* b2       = (const float*)d_in[13];

    // workspace layout (all 16B-aligned):
    char* ws = (char*)d_ws;
    uint4*    leftbf  = (uint4*)ws;                                   // 2 MB
    uint4*    rightbf = (uint4*)(ws + (size_t)N_RES * 64);            // 2 MB
    uint32_t* meta    = (uint32_t*)(ws + (size_t)2 * N_RES * 64);     // 128 KB
    uint32_t* wposbf  = (uint32_t*)(ws + (size_t)2 * N_RES * 64 + N_RES * 4); // 4.2 KB

    float* out_logp = (float*)d_out;
    float* out_dmap = out_logp + (size_t)N_RES * KNEI * NBINS;

    proj_kernel<<<1024, 256, 0, stream>>>(features, W_left, W_right,
                                          resi, chain, batch, W_pos,
                                          leftbf, rightbf, meta, wposbf);
    pair_kernel<<<2048, 256, 0, stream>>>(leftbf, rightbf, meta, nbr, wposbf,
                                          ln_scale, ln_bias, W1, b1, W2, b2,
                                          out_logp, out_dmap);
}